// Round 6
// baseline (18.734 us; speedup 1.0000x reference)
//
#include <hip/hip_runtime.h>
#include <hip/hip_fp16.h>

#define NPAIR (512 * 512)
#define NL 5
#define NH 8
#define ND 16
#define NE 10000
#define TPB 256
#define GRID (NPAIR / TPB)               // 1024 blocks = 4/CU * 256 CU, co-resident
#define NROWS (NE * NL)                  // 50000 table rows (e,l)
#define NWBLK ((NROWS + TPB - 1) / TPB)  // 196 writer blocks
#define NPOLL (NWBLK / 4)                // 49 poller lanes x dwordx4 = 196 flags
#define FLAGS_OFF (1u << 20)             // flags at d_ws + 1MB (T uses 800KB)

typedef unsigned u32x4 __attribute__((ext_vector_type(4)));

__device__ __forceinline__ unsigned magic_of(int i) {
    return 0xA5C37E19u ^ ((unsigned)i * 0x9E3779B1u);
}

// flag store: RELAXED agent atomic -> sc1 dword store (to L3), no cache maint.
__device__ __forceinline__ void flag_store(unsigned* p, unsigned v) {
    __hip_atomic_store(p, v, __ATOMIC_RELAXED, __HIP_MEMORY_SCOPE_AGENT);
}

// Single plain dispatch.
//  Phase A: threads g<50000 build T[e][l][h] fp16, stored WRITE-THROUGH to L3
//           (sc0 sc1) -- no dirty L2, no wbl2.
//  Barrier: per-thread vmcnt drain -> block flag (magic, poison-proof);
//           ALL blocks poll the 196 flags directly (49 lanes x dwordx4 sc0 sc1,
//           single writer->reader hop).
//  Phase B: 5 x 16B T-gathers per pair via PLAIN CACHED loads: dispatch-start
//           L2 invalidate (proven round 1) + write-through T means no stale
//           line can exist; T is L2-resident with ~26x row reuse.
__global__ __launch_bounds__(256, 4) void edge_onepass(
    const float* __restrict__ F,    // [E, D]
    const float* __restrict__ Wg,   // [L+1, H*D]
    const int* __restrict__ sp,     // [NPAIR, L] int32
    float* __restrict__ out,        // [H, NPAIR]
    const __half* __restrict__ T,   // [NROWS, NH] fp16 workspace
    unsigned* __restrict__ flags)   // [256] workspace
{
    __shared__ int spL[TPB * NL];   // 1280 ints
    const int tid = threadIdx.x;
    const int bid = blockIdx.x;
    const int g = bid * TPB + tid;

    // ---- issue sp staging first: latency hides under phase A ----
    const int4* __restrict__ spv = (const int4*)(sp + (size_t)bid * (TPB * NL));
    int4* spd = (int4*)spL;
#pragma unroll
    for (int i = 0; i < 2; ++i) {
        const int k = tid + i * TPB;
        if (k < (TPB * NL) / 4) spd[k] = spv[k];
    }

    // ---- Phase A: build fp16 table (blocks 0..195) ----
    if (g < NROWS) {
        const int e = g / NL;
        const int l = g - e * NL;
        const float4* __restrict__ fp = (const float4*)(F + (size_t)e * ND);
        const float4 f0 = fp[0], f1 = fp[1], f2 = fp[2], f3 = fp[3];
        const float* __restrict__ w0 = Wg + NH * ND + l * NH * ND;  // W row 1+l

        union { u32x4 u4; __half2 h2[4]; } s;
#pragma unroll
        for (int hh = 0; hh < 4; ++hh) {
            float r2[2];
#pragma unroll
            for (int k = 0; k < 2; ++k) {
                const int h = hh * 2 + k;
                const float4* __restrict__ wp = (const float4*)(w0 + h * ND);
                const float4 wa = wp[0], wb = wp[1], wc = wp[2], wd = wp[3];
                float a;
                a  = f0.x * wa.x + f0.y * wa.y + f0.z * wa.z + f0.w * wa.w;
                a += f1.x * wb.x + f1.y * wb.y + f1.z * wb.z + f1.w * wb.w;
                a += f2.x * wc.x + f2.y * wc.y + f2.z * wc.z + f2.w * wc.w;
                a += f3.x * wd.x + f3.y * wd.y + f3.z * wd.z + f3.w * wd.w;
                r2[k] = a;
            }
            s.h2[hh] = __floats2half2_rn(r2[0], r2[1]);
        }
        const unsigned long long ta =
            (unsigned long long)(uintptr_t)(T + (size_t)g * NH);
        // write-through to L3: device-visible once vmcnt retires
        asm volatile("global_store_dwordx4 %0, %1, off sc0 sc1"
                     :: "v"(ta), "v"(s.u4) : "memory");
    }

    // per-thread drain: T stores acked at L3 before this block's flag goes up
    if (bid < NWBLK) asm volatile("s_waitcnt vmcnt(0)" ::: "memory");
    __syncthreads();                 // also completes spL staging
    if (bid < NWBLK && tid == 0) flag_store(&flags[bid], magic_of(bid));

    // ---- pre-barrier: compute gather addresses/masks from LDS (overlaps wait)
    float m[NL], cnt = 0.f;
    const u32x4* ta[NL];
#pragma unroll
    for (int l = 0; l < NL; ++l) {
        const int e = spL[tid * NL + l];          // stride-5, conflict-free
        m[l] = (e >= 0) ? 1.f : 0.f;
        cnt += m[l];
        const int row = ((e >= 0) ? e : 0) * NL + l;
        ta[l] = (const u32x4*)(T + (size_t)row * NH);
    }

    // ---- barrier: 49 lanes poll all 196 flags via dwordx4 sc0 sc1 ----
    if (tid < NPOLL) {
        const int b4 = tid * 4;
        const unsigned m0 = magic_of(b4 + 0), m1 = magic_of(b4 + 1);
        const unsigned m2 = magic_of(b4 + 2), m3 = magic_of(b4 + 3);
        const unsigned long long fa =
            (unsigned long long)(uintptr_t)(flags + b4);
        while (true) {
            u32x4 v;
            asm volatile("global_load_dwordx4 %0, %1, off sc0 sc1\n\t"
                         "s_waitcnt vmcnt(0)"
                         : "=v"(v) : "v"(fa) : "memory");
            if (v[0] == m0 && v[1] == m1 && v[2] == m2 && v[3] == m3) break;
            __builtin_amdgcn_s_sleep(1);
        }
    }
    __syncthreads();

    // ---- Phase B: plain cached gathers (L2-served, ~26x row reuse) ----
    u32x4 tv[NL];
#pragma unroll
    for (int l = 0; l < NL; ++l) tv[l] = ta[l][0];

    float acc[NH];
#pragma unroll
    for (int h = 0; h < NH; ++h) acc[h] = 0.f;
#pragma unroll
    for (int l = 0; l < NL; ++l) {
        const float ml = m[l];
#pragma unroll
        for (int hh = 0; hh < 4; ++hh) {
            const unsigned u = tv[l][hh];
            __half2 p; __builtin_memcpy(&p, &u, 4);
            const float2 v = __half22float2(p);
            acc[hh * 2 + 0] += ml * v.x;
            acc[hh * 2 + 1] += ml * v.y;
        }
    }

    const float r = 1.0f / fmaxf(cnt, 1.f);
    const size_t p = (size_t)g;
#pragma unroll
    for (int h = 0; h < NH; ++h)
        __builtin_nontemporal_store(acc[h] * r, out + (size_t)h * NPAIR + p);
}

extern "C" void kernel_launch(void* const* d_in, const int* in_sizes, int n_in,
                              void* d_out, int out_size, void* d_ws, size_t ws_size,
                              hipStream_t stream) {
    (void)in_sizes; (void)n_in; (void)out_size; (void)ws_size;
    const float* F  = (const float*)d_in[0];   // edge_features_s [E, D]
    const float* Wg = (const float*)d_in[1];   // edge_weights [L+1, H*D]
    const int*   sp = (const int*)d_in[2];     // shortest_path_edges [N,N,L] int32
    float* out = (float*)d_out;                // [H, N, N]
    __half* T = (__half*)d_ws;                 // 800 KB table
    unsigned* flags = (unsigned*)((char*)d_ws + FLAGS_OFF);

    edge_onepass<<<GRID, TPB, 0, stream>>>(F, Wg, sp, out, T, flags);
}

// Round 7
// 16.685 us; speedup vs baseline: 1.1228x; 1.1228x over previous
//
#include <hip/hip_runtime.h>
#include <hip/hip_fp16.h>

#define NPAIR (512 * 512)
#define NL 5
#define NH 8
#define ND 16
#define NE 10000
#define TPB 256
#define GRID (NPAIR / TPB)               // 1024 blocks = 4/CU * 256 CU, co-resident
#define NROWS (NE * NL)                  // 50000 table rows (e,l)
#define NWBLK ((NROWS + TPB - 1) / TPB)  // 196 writer blocks
#define FLAGS_OFF (1u << 20)             // flags at d_ws + 1MB (T uses 800KB)
#define DONE_IDX 200

typedef unsigned u32x4 __attribute__((ext_vector_type(4)));

__device__ __forceinline__ unsigned magic_of(int i) {
    return 0xA5C37E19u ^ ((unsigned)i * 0x9E3779B1u);
}
#define DONE_MAGIC 0x5EC0FFEEu

// flag ops: RELAXED agent atomics -> plain sc1 dword load/store, no cache maint
__device__ __forceinline__ void flag_store(unsigned* p, unsigned v) {
    __hip_atomic_store(p, v, __ATOMIC_RELAXED, __HIP_MEMORY_SCOPE_AGENT);
}
__device__ __forceinline__ unsigned flag_load(unsigned* p) {
    return __hip_atomic_load(p, __ATOMIC_RELAXED, __HIP_MEMORY_SCOPE_AGENT);
}

// R5 skeleton (16.8us) with ONE change: phase-B T gathers are plain cached
// loads (L2-resident, ~26x row reuse) instead of sc0sc1 L3-forced loads.
// Barrier: writers -> 196 magic flags; block 0 aggregates -> single DONE
// line; 1023 blocks poll one shared line (near-zero poll traffic).
// Correctness of plain gathers proven by R6 passing: dispatch-start acquire
// invalidates L2s; within-dispatch T writes are write-through (sc0 sc1),
// so no stale-valid T line can exist.
__global__ __launch_bounds__(256, 4) void edge_onepass(
    const float* __restrict__ F,    // [E, D]
    const float* __restrict__ Wg,   // [L+1, H*D]
    const int* __restrict__ sp,     // [NPAIR, L] int32
    float* __restrict__ out,        // [H, NPAIR]
    const __half* __restrict__ T,   // [NROWS, NH] fp16 workspace
    unsigned* __restrict__ flags)   // [256] workspace
{
    __shared__ int spL[TPB * NL];   // 1280 ints
    const int tid = threadIdx.x;
    const int bid = blockIdx.x;
    const int g = bid * TPB + tid;

    // ---- issue sp staging first: latency hides under phase A ----
    const int4* __restrict__ spv = (const int4*)(sp + (size_t)bid * (TPB * NL));
    int4* spd = (int4*)spL;
#pragma unroll
    for (int i = 0; i < 2; ++i) {
        const int k = tid + i * TPB;
        if (k < (TPB * NL) / 4) spd[k] = spv[k];
    }

    // ---- Phase A: build fp16 table (blocks 0..195) ----
    if (g < NROWS) {
        const int e = g / NL;
        const int l = g - e * NL;
        const float4* __restrict__ fp = (const float4*)(F + (size_t)e * ND);
        const float4 f0 = fp[0], f1 = fp[1], f2 = fp[2], f3 = fp[3];
        const float* __restrict__ w0 = Wg + NH * ND + l * NH * ND;  // W row 1+l

        union { u32x4 u4; __half2 h2[4]; } s;
#pragma unroll
        for (int hh = 0; hh < 4; ++hh) {
            float r2[2];
#pragma unroll
            for (int k = 0; k < 2; ++k) {
                const int h = hh * 2 + k;
                const float4* __restrict__ wp = (const float4*)(w0 + h * ND);
                const float4 wa = wp[0], wb = wp[1], wc = wp[2], wd = wp[3];
                float a;
                a  = f0.x * wa.x + f0.y * wa.y + f0.z * wa.z + f0.w * wa.w;
                a += f1.x * wb.x + f1.y * wb.y + f1.z * wb.z + f1.w * wb.w;
                a += f2.x * wc.x + f2.y * wc.y + f2.z * wc.z + f2.w * wc.w;
                a += f3.x * wd.x + f3.y * wd.y + f3.z * wd.z + f3.w * wd.w;
                r2[k] = a;
            }
            s.h2[hh] = __floats2half2_rn(r2[0], r2[1]);
        }
        const unsigned long long ta =
            (unsigned long long)(uintptr_t)(T + (size_t)g * NH);
        // write-through to L3: device-visible once vmcnt retires
        asm volatile("global_store_dwordx4 %0, %1, off sc0 sc1"
                     :: "v"(ta), "v"(s.u4) : "memory");
    }

    // per-thread drain: T stores acked at L3 before this block's flag goes up
    if (bid < NWBLK) asm volatile("s_waitcnt vmcnt(0)" ::: "memory");
    __syncthreads();                 // also completes spL staging
    if (bid < NWBLK && tid == 0) flag_store(&flags[bid], magic_of(bid));

    // ---- pre-barrier: gather addresses/masks from LDS (overlaps the wait) ----
    float m[NL], cnt = 0.f;
    const u32x4* ta[NL];
#pragma unroll
    for (int l = 0; l < NL; ++l) {
        const int e = spL[tid * NL + l];          // stride-5, conflict-free
        m[l] = (e >= 0) ? 1.f : 0.f;
        cnt += m[l];
        const int row = ((e >= 0) ? e : 0) * NL + l;
        ta[l] = (const u32x4*)(T + (size_t)row * NH);
    }

    // ---- barrier: block 0 aggregates 196 flags; everyone else polls DONE ----
    if (bid == 0) {
        if (tid < NWBLK) {
            const unsigned want = magic_of(tid);
            while (flag_load(&flags[tid]) != want)
                __builtin_amdgcn_s_sleep(1);
        }
        __syncthreads();
        if (tid == 0) flag_store(&flags[DONE_IDX], DONE_MAGIC);
    } else {
        if (tid == 0) {
            while (flag_load(&flags[DONE_IDX]) != DONE_MAGIC)
                __builtin_amdgcn_s_sleep(4);
        }
        __syncthreads();
    }

    // ---- Phase B: plain cached gathers (L2-served, ~26x row reuse) ----
    u32x4 tv[NL];
#pragma unroll
    for (int l = 0; l < NL; ++l) tv[l] = ta[l][0];

    float acc[NH];
#pragma unroll
    for (int h = 0; h < NH; ++h) acc[h] = 0.f;
#pragma unroll
    for (int l = 0; l < NL; ++l) {
        const float ml = m[l];
#pragma unroll
        for (int hh = 0; hh < 4; ++hh) {
            const unsigned u = tv[l][hh];
            __half2 p; __builtin_memcpy(&p, &u, 4);
            const float2 v = __half22float2(p);
            acc[hh * 2 + 0] += ml * v.x;
            acc[hh * 2 + 1] += ml * v.y;
        }
    }

    const float r = 1.0f / fmaxf(cnt, 1.f);
    const size_t p = (size_t)g;
#pragma unroll
    for (int h = 0; h < NH; ++h)
        __builtin_nontemporal_store(acc[h] * r, out + (size_t)h * NPAIR + p);
}

extern "C" void kernel_launch(void* const* d_in, const int* in_sizes, int n_in,
                              void* d_out, int out_size, void* d_ws, size_t ws_size,
                              hipStream_t stream) {
    (void)in_sizes; (void)n_in; (void)out_size; (void)ws_size;
    const float* F  = (const float*)d_in[0];   // edge_features_s [E, D]
    const float* Wg = (const float*)d_in[1];   // edge_weights [L+1, H*D]
    const int*   sp = (const int*)d_in[2];     // shortest_path_edges [N,N,L] int32
    float* out = (float*)d_out;                // [H, N, N]
    __half* T = (__half*)d_ws;                 // 800 KB table
    unsigned* flags = (unsigned*)((char*)d_ws + FLAGS_OFF);

    edge_onepass<<<GRID, TPB, 0, stream>>>(F, Wg, sp, out, T, flags);
}